// Round 1
// baseline (4778.548 us; speedup 1.0000x reference)
//
#include <hip/hip_runtime.h>
#include <hip/hip_bf16.h>

// ---------------- problem constants ----------------
#define TSEQ 512
#define NB   64
#define NE   256
#define NH   512
#define NG   2048   // 4*NH

// ---------------- workspace layout (bytes) ----------------
static const size_t OFF_W1  = 0;           // 6,291,456
static const size_t OFF_W2  = 6291456;     // 8,388,608
static const size_t OFF_X   = 14680064;    // 16,777,216  (fragment-linear per t)
static const size_t OFF_H1  = 31457280;    // data ring L1: 2 dir * 3 slot * 64KB = 393,216
static const size_t OFF_H2  = 31850496;    // data ring L2: 393,216
static const size_t OFF_S1  = 32243712;    // shadow ring L1 (= OFF_H1 + 786,432)
static const size_t OFF_S2  = 32636928;    // shadow ring L2 (= OFF_H2 + 786,432)
static const size_t OFF_HF  = 33030144;    // 131,072
static const size_t OFF_CNT = 33161216;    // hint tags: 4 sets * 16 rep * 256 * 4B = 64 KB
// end = 33,226,752

// shadow plane sits exactly +786,432 bytes (= +393,216 bf16) after its data plane
#define SHDELTA 393216

typedef __bf16 v8bf __attribute__((ext_vector_type(8)));
typedef float  v4f  __attribute__((ext_vector_type(4)));

#define MFMA16(a_, b_, c_) __builtin_amdgcn_mfma_f32_16x16x32_bf16((a_), (b_), (c_), 0, 0, 0)

// Coherent 16B h-fragment load: two 8B relaxed agent-scope atomic loads.
static __device__ __forceinline__ v8bf load_h8(const __bf16* p) {
    unsigned long long lo = __hip_atomic_load((unsigned long long*)p,     __ATOMIC_RELAXED, __HIP_MEMORY_SCOPE_AGENT);
    unsigned long long hi = __hip_atomic_load((unsigned long long*)p + 1, __ATOMIC_RELAXED, __HIP_MEMORY_SCOPE_AGENT);
    union { unsigned long long q[2]; v8bf v; } u;
    u.q[0] = lo; u.q[1] = hi;
    return u.v;
}

static __device__ __forceinline__ unsigned short bf16_bits(float f) {
    __bf16 b = (__bf16)f;
    return __builtin_bit_cast(unsigned short, b);
}

// Value-validated publication check.
// Accept fragment iff shadow == data ^ M(gen) per 16-bit lane. |h| <= 1.0 means
// bit14 (exponent MSB) of every valid h is 0; M alternates 0x4000 per ring
// generation, so any stale/mixed generation combo would need h_new == h_old^0x4000
// (|.| >= 2) -> impossible. Cross-gen accepts are value-identical (benign).
static __device__ __forceinline__ unsigned frag_ok(v8bf d, v8bf sh, unsigned m) {
    union { v8bf v; unsigned u[4]; } a, b;
    a.v = d; b.v = sh;
    unsigned x = (a.u[0] ^ b.u[0] ^ m) | (a.u[1] ^ b.u[1] ^ m)
               | (a.u[2] ^ b.u[2] ^ m) | (a.u[3] ^ b.u[3] ^ m);
    return (unsigned)(x == 0u);
}

// Load 16 D-fragments + 16 S-fragments, retry until all validate.
// Uses q/aoff from enclosing scope.
#define LOAD_VALIDATE16(dst_, base_, mm_)                                      \
    {                                                                          \
        const __bf16* _b  = (base_);                                           \
        const __bf16* _sb = _b + SHDELTA;                                      \
        const unsigned _m = (mm_);                                             \
        while (true) {                                                         \
            v8bf _sh[16];                                                      \
            _Pragma("unroll")                                                  \
            for (int c = 0; c < 16; ++c) {                                     \
                dst_[c] = load_h8(_b  + (4 * c + q) * 512 + aoff);             \
                _sh[c]  = load_h8(_sb + (4 * c + q) * 512 + aoff);             \
            }                                                                  \
            __builtin_amdgcn_sched_barrier(0);                                 \
            unsigned _ok = 1u;                                                 \
            _Pragma("unroll")                                                  \
            for (int c = 0; c < 16; ++c) _ok &= frag_ok(dst_[c], _sh[c], _m);  \
            if (__all((int)_ok)) break;                                        \
        }                                                                      \
    }

// ---------------- phase A: weight convert to fragment-linear bf16 ----------------
__global__ void wconv_kernel(const float* __restrict__ Wf, const float* __restrict__ Uf,
                             const float* __restrict__ Wb, const float* __restrict__ Ub,
                             char* __restrict__ dst, int NC, int KX)
{
    int id = blockIdx.x * 256 + threadIdx.x;
    int j    = id & 7;
    int lane = (id >> 3) & 63;
    int t    = (id >> 9) & 1;
    int rest = id >> 10;            // (dir*64+slice)*NC + c
    int c    = rest % NC;
    int ds   = rest / NC;
    int slice = ds & 63;
    int dirr  = ds >> 6;
    int coll = t * 16 + (lane & 15);
    int k    = c * 32 + (lane >> 4) * 8 + j;
    int gate = coll >> 3, jjj = coll & 7;
    int zcol = gate * 512 + slice * 8 + jjj;
    const float* W = dirr ? Wb : Wf;
    const float* U = dirr ? Ub : Uf;
    float v = (k < KX) ? W[(size_t)k * NG + zcol] : U[(size_t)(k - KX) * NG + zcol];
    ((__bf16*)dst)[id] = (__bf16)v;
}

// ---------------- phase A: embedding gather into fragment-linear X + ring/tag init ----------------
// X element (t, b=m, e) stored at byte: t*32768 + ((e>>3)*64 + m)*16 + (e&7)*2
__global__ void gather_x_kernel(const int* __restrict__ tokens, const float* __restrict__ emb,
                                char* __restrict__ ws)
{
    size_t id = (size_t)blockIdx.x * 256 + threadIdx.x;
    int j  = (int)(id & 7);
    int m  = (int)((id >> 3) & 63);
    int kb = (int)((id >> 9) & 31);
    int t  = (int)(id >> 14);
    int tok = tokens[m * TSEQ + t];
    float v = emb[(size_t)tok * NE + kb * 8 + j];
    ((__bf16*)(ws + OFF_X))[(size_t)t * 16384 + (kb * 64 + m) * 8 + j] = (__bf16)v;
    // ring init: D planes (H1+H2, contiguous 786,432B) = 0.0; S planes = 1.0 pattern.
    // (0,1.0) never validates under either mask; mixed init/new accepts are benign
    // (accept only when loaded D equals the true value).
    if (id < 393216) {
        ((unsigned*)(ws + OFF_H1))[id] = (id < 196608) ? 0u : 0x3F803F80u;
    }
    if (id < 16384) ((int*)(ws + OFF_CNT))[id] = 0;    // all hint replicas
}

// ---------------- phase B: persistent pipelined recurrence ----------------
// Same MFMA/gate structure as the proven kernel, but publication is drain-free:
//   producer: store data + shadow(=data^M(gen)), then store un-drained hint tags.
//   consumer: spin on hints (cheap), then load D+S and value-validate (retry rare).
// Ring depth 3 (slot = s mod 3); generation mask alternates per wrap.
// L2 is split: h1 phase (slack-hidden, L1 runs ahead) before the critical h2 spin.
template<int LAYER>
__device__ void run_layer(char* __restrict__ ws, const char* __restrict__ smem,
                          int dir, int slice, int tid,
                          const float* __restrict__ bb)
{
    const int lane = tid & 63;
    const int wv   = tid >> 6;
    const int colc = lane & 15;
    const int q    = lane >> 4;
    const int m0   = wv * 16;
    const int jj   = colc & 7;
    const int hcol = slice * 8 + jj;

    __bf16* h1ring = (__bf16*)(ws + OFF_H1 + (size_t)dir * (3 * 65536));
    __bf16* h2ring = (__bf16*)(ws + OFF_H2 + (size_t)dir * (3 * 65536));
    const char* Xfrag = ws + OFF_X;
    __bf16* hfin = (__bf16*)(ws + OFF_HF) + (size_t)dir * (NB * NH);

    // hints: T[(dir*2+layer)*4096 + rep*256 + wv*64 + slice]
    int* T = (int*)(ws + OFF_CNT);
    const int rep = ((slice << 2) | wv) & 15;
    int* p1   = T + (dir * 2 + 0) * 4096 + rep * 256 + wv * 64 + lane;   // L1 hints
    int* p2   = T + (dir * 2 + 1) * 4096 + rep * 256 + wv * 64 + lane;   // L2 hints
    int* ownb = T + (dir * 2 + LAYER) * 4096;                             // publish base

    const float bi  = bb[hcol];
    const float bf_ = bb[512 + hcol];
    const float bg  = bb[1024 + hcol];
    const float bo  = bb[1536 + hcol];

    float cst[4] = {0.f, 0.f, 0.f, 0.f};

    // h-fragment element offset for consumer loads (in __bf16 units)
    const int aoff = (m0 + colc) * 8;

    // ring-3 slot state: cs/cp = slot & gen-parity of step s; ps/pp = of step s-1
    int cs = 0, ps = 0, cp = 0, pp = 0;

    #pragma unroll 1
    for (int s = 0; s < TSEQ; ++s) {
        v4f acc0a = {0,0,0,0}, acc1a = {0,0,0,0};
        v4f acc0b = {0,0,0,0}, acc1b = {0,0,0,0};

        if (LAYER == 0) {
            // ---- L1: x-part (no step dependency) BEFORE any spin ----
            {
                const int xs = dir ? (TSEQ - 1 - s) : s;
                const char* xb = Xfrag + (size_t)xs * 32768;
                #pragma unroll
                for (int c = 0; c < 8; ++c) {
                    v8bf a  = *(const v8bf*)(xb + (((4 * c + q) * 64 + m0 + colc) * 16));
                    v8bf w0 = *(const v8bf*)(smem + (c * 2 + 0) * 1024 + lane * 16);
                    v8bf w1 = *(const v8bf*)(smem + (c * 2 + 1) * 1024 + lane * 16);
                    if (c & 1) { acc0b = MFMA16(a, w0, acc0b); acc1b = MFMA16(a, w1, acc1b); }
                    else       { acc0a = MFMA16(a, w0, acc0a); acc1a = MFMA16(a, w1, acc1a); }
                }
            }
            // ---- spin: peers' h1[s-1] issued (p1>=s), ring guard (p2>=s-2, ring-3) ----
            {
                const int t1 = s;
                const int t2 = s - 2;
                if (t1 > 0) {
                    while (true) {
                        int v1 = __hip_atomic_load(p1, __ATOMIC_RELAXED, __HIP_MEMORY_SCOPE_AGENT);
                        bool ok = (v1 >= t1);
                        if (t2 > 0) {
                            int v2 = __hip_atomic_load(p2, __ATOMIC_RELAXED, __HIP_MEMORY_SCOPE_AGENT);
                            ok = ok && (v2 >= t2);
                        }
                        if (__all(ok)) break;
                    }
                }
            }
            // ---- h1[s-1]-dependent MFMA work (value-validated loads) ----
            if (s > 0) {
                v8bf ah[16];
                LOAD_VALIDATE16(ah, h1ring + (size_t)ps * 32768, pp ? 0x40004000u : 0u);
                #pragma unroll
                for (int c = 0; c < 16; ++c) {
                    v8bf w0 = *(const v8bf*)(smem + ((8 + c) * 2 + 0) * 1024 + lane * 16);
                    v8bf w1 = *(const v8bf*)(smem + ((8 + c) * 2 + 1) * 1024 + lane * 16);
                    if (c & 1) { acc0b = MFMA16(ah[c], w0, acc0b); acc1b = MFMA16(ah[c], w1, acc1b); }
                    else       { acc0a = MFMA16(ah[c], w0, acc0a); acc1a = MFMA16(ah[c], w1, acc1a); }
                }
            }
        } else {
            // ---- L2 phase 1: h1[s] feed (L1 runs ahead; off the h2 self-loop) ----
            {
                const int t1 = s + 1;
                while (true) {
                    int v1 = __hip_atomic_load(p1, __ATOMIC_RELAXED, __HIP_MEMORY_SCOPE_AGENT);
                    if (__all(v1 >= t1)) break;
                }
            }
            {
                v8bf a0[16];
                LOAD_VALIDATE16(a0, h1ring + (size_t)cs * 32768, cp ? 0x40004000u : 0u);
                #pragma unroll
                for (int c = 0; c < 16; ++c) {
                    v8bf w0 = *(const v8bf*)(smem + (c * 2 + 0) * 1024 + lane * 16);
                    v8bf w1 = *(const v8bf*)(smem + (c * 2 + 1) * 1024 + lane * 16);
                    if (c & 1) { acc0b = MFMA16(a0[c], w0, acc0b); acc1b = MFMA16(a0[c], w1, acc1b); }
                    else       { acc0a = MFMA16(a0[c], w0, acc0a); acc1a = MFMA16(a0[c], w1, acc1a); }
                }
            }
            // ---- L2 phase 2: critical h2[s-1] self-loop ----
            if (s > 0) {
                while (true) {
                    int v2 = __hip_atomic_load(p2, __ATOMIC_RELAXED, __HIP_MEMORY_SCOPE_AGENT);
                    if (__all(v2 >= s)) break;
                }
                v8bf a1[16];
                LOAD_VALIDATE16(a1, h2ring + (size_t)ps * 32768, pp ? 0x40004000u : 0u);
                #pragma unroll
                for (int c = 0; c < 16; ++c) {
                    v8bf w0 = *(const v8bf*)(smem + ((16 + c) * 2 + 0) * 1024 + lane * 16);
                    v8bf w1 = *(const v8bf*)(smem + ((16 + c) * 2 + 1) * 1024 + lane * 16);
                    if (c & 1) { acc0b = MFMA16(a1[c], w0, acc0b); acc1b = MFMA16(a1[c], w1, acc1b); }
                    else       { acc0a = MFMA16(a1[c], w0, acc0a); acc1a = MFMA16(a1[c], w1, acc1a); }
                }
            }
        }

        v4f z0 = acc0a + acc0b;   // gates i (cols 0-7) / f (cols 8-15)
        v4f z1 = acc1a + acc1b;   // gates g / o

        // ---- gate nonlinearity; lanes col and col^8 exchange ----
        float hv[4];
        #pragma unroll
        for (int r = 0; r < 4; ++r) {
            float p0 = __shfl_xor(z0[r], 8, 64);
            float p1v = __shfl_xor(z1[r], 8, 64);
            float zi, zf, zg, zo;
            if (colc < 8) { zi = z0[r]; zf = p0;    zg = z1[r]; zo = p1v;   }
            else          { zi = p0;    zf = z0[r]; zg = p1v;   zo = z1[r]; }
            zi += bi; zf += bf_; zg += bg; zo += bo;
            float gi = 1.f / (1.f + __expf(-zi));
            float gf = 1.f / (1.f + __expf(-zf));
            float gg = 1.f - 2.f / (1.f + __expf(2.f * zg));   // tanh
            float go = 1.f / (1.f + __expf(-zo));
            float cn = gf * cst[r] + gi * gg;
            cst[r] = cn;
            float th = 1.f - 2.f / (1.f + __expf(2.f * cn));   // tanh
            hv[r] = go * th;
        }

        // ---- drain-free publication: data + shadow(=data^M), then hints ----
        __bf16* hd = (LAYER ? h2ring : h1ring) + (size_t)cs * 32768;
        const unsigned mw = cp ? 0x40004000u : 0u;
        #pragma unroll
        for (int r = 0; r < 4; ++r) {
            float pv = __shfl_xor(hv[r], 1, 64);
            int m = m0 + q * 4 + r;
            if (((colc & 1) == 0) && (colc < 8)) {
                unsigned val = (unsigned)bf16_bits(hv[r]) | ((unsigned)bf16_bits(pv) << 16);
                __hip_atomic_store((unsigned*)(hd + (slice * 64 + m) * 8 + colc), val,
                                   __ATOMIC_RELAXED, __HIP_MEMORY_SCOPE_AGENT);
                __hip_atomic_store((unsigned*)(hd + SHDELTA + (slice * 64 + m) * 8 + colc), val ^ mw,
                                   __ATOMIC_RELAXED, __HIP_MEMORY_SCOPE_AGENT);
            }
            if (LAYER == 1 && s == TSEQ - 1 && colc < 8)
                hfin[(size_t)m * NH + hcol] = (__bf16)hv[r];   // kernel boundary publishes
        }

        // keep hint stores after data/shadow in the emitted schedule (no waitcnt!)
        __builtin_amdgcn_sched_barrier(0);
        if (lane < 16)
            __hip_atomic_store(ownb + lane * 256 + wv * 64 + slice, s + 1,
                               __ATOMIC_RELAXED, __HIP_MEMORY_SCOPE_AGENT);

        // ---- ring-3 slot/generation update ----
        ps = cs; pp = cp;
        cs = (cs == 2) ? 0 : cs + 1;
        if (cs == 0) cp ^= 1;
    }
}

__global__ __launch_bounds__(256, 1) void lstm_persist(
    char* __restrict__ ws,
    const float* __restrict__ b1f, const float* __restrict__ b2f,
    const float* __restrict__ b1b, const float* __restrict__ b2b)
{
    const int tid   = threadIdx.x;
    const int bid   = blockIdx.x;       // 256 wgs
    const int dir   = bid >> 7;
    const int layer = (bid >> 6) & 1;
    const int slice = bid & 63;

    const int NC = layer ? 32 : 24;
    const int wbytes = NC * 2048;       // 48KB (L1) / 64KB (L2)

    __shared__ char smem[65536];
    {
        const char* wsrc = ws + (layer ? OFF_W2 : OFF_W1)
                         + (size_t)(dir * 64 + slice) * (size_t)wbytes;
        for (int i = tid * 16; i < wbytes; i += 256 * 16)
            *(uint4*)(smem + i) = *(const uint4*)(wsrc + i);
    }
    __syncthreads();   // staging is cooperative; only barrier in the kernel

    const float* bb = layer ? (dir ? b2b : b2f) : (dir ? b1b : b1f);
    if (layer == 0) run_layer<0>(ws, smem, dir, slice, tid, bb);
    else            run_layer<1>(ws, smem, dir, slice, tid, bb);
}

// ---------------- phase C: dense head [64,1024]@[1024,5]+bd ----------------
__global__ void head_kernel(const char* __restrict__ ws, const float* __restrict__ Wd,
                            const float* __restrict__ bd, float* __restrict__ out)
{
    int b = blockIdx.x;
    int lane = threadIdx.x;   // 64
    const __bf16* hfF = (const __bf16*)(ws + OFF_HF) + (size_t)b * NH;
    const __bf16* hfB = (const __bf16*)(ws + OFF_HF) + (size_t)(NB * NH) + (size_t)b * NH;
    #pragma unroll
    for (int o = 0; o < 5; ++o) {
        float sum = 0.f;
        for (int k = lane; k < 2 * NH; k += 64) {
            float fv = (k < NH) ? (float)hfF[k] : (float)hfB[k - NH];
            sum += fv * Wd[(size_t)k * 5 + o];
        }
        #pragma unroll
        for (int off = 32; off > 0; off >>= 1) sum += __shfl_down(sum, off, 64);
        if (lane == 0) out[b * 5 + o] = sum + bd[o];
    }
}

// ---------------- launch ----------------
extern "C" void kernel_launch(void* const* d_in, const int* in_sizes, int n_in,
                              void* d_out, int out_size, void* d_ws, size_t ws_size,
                              hipStream_t stream)
{
    const int*   tokens = (const int*)  d_in[0];
    const float* emb    = (const float*)d_in[1];
    const float* W1f    = (const float*)d_in[2];
    const float* U1f    = (const float*)d_in[3];
    const float* b1f    = (const float*)d_in[4];
    const float* W2f    = (const float*)d_in[5];
    const float* U2f    = (const float*)d_in[6];
    const float* b2f    = (const float*)d_in[7];
    const float* W1b    = (const float*)d_in[8];
    const float* U1b    = (const float*)d_in[9];
    const float* b1b    = (const float*)d_in[10];
    const float* W2b    = (const float*)d_in[11];
    const float* U2b    = (const float*)d_in[12];
    const float* b2b    = (const float*)d_in[13];
    const float* Wd     = (const float*)d_in[14];
    const float* bd     = (const float*)d_in[15];
    char* ws = (char*)d_ws;

    wconv_kernel<<<12288, 256, 0, stream>>>(W1f, U1f, W1b, U1b, ws + OFF_W1, 24, 256);
    wconv_kernel<<<16384, 256, 0, stream>>>(W2f, U2f, W2b, U2b, ws + OFF_W2, 32, 512);
    gather_x_kernel<<<32768, 256, 0, stream>>>(tokens, emb, ws);
    lstm_persist<<<256, 256, 0, stream>>>(ws, b1f, b2f, b1b, b2b);
    head_kernel<<<NB, 64, 0, stream>>>(ws, Wd, bd, (float*)d_out);
}

// Round 2
// 3675.003 us; speedup vs baseline: 1.3003x; 1.3003x over previous
//
#include <hip/hip_runtime.h>
#include <hip/hip_bf16.h>

// ---------------- problem constants ----------------
#define TSEQ 512
#define NB   64
#define NE   256
#define NH   512
#define NG   2048   // 4*NH

// ---------------- workspace layout (bytes) ----------------
static const size_t OFF_W1  = 0;          // 6,291,456
static const size_t OFF_W2  = 6291456;    // 8,388,608
static const size_t OFF_X   = 14680064;   // 16,777,216  (fragment-linear per t)
static const size_t OFF_H1  = 31457280;   // 2 dir * 4 slot * 64KB = 524,288
static const size_t OFF_H2  = 31981568;   // 524,288
static const size_t OFF_HF  = 32505856;   // 131,072
static const size_t OFF_CNT = 32636928;   // tags: 4 sets * 16 rep * 256 * 4B = 64 KB

typedef __bf16 v8bf __attribute__((ext_vector_type(8)));
typedef float  v4f  __attribute__((ext_vector_type(4)));

#define MFMA16(a_, b_, c_) __builtin_amdgcn_mfma_f32_16x16x32_bf16((a_), (b_), (c_), 0, 0, 0)

// Coherent 16B h-fragment load: two 8B relaxed agent-scope atomic loads.
static __device__ __forceinline__ v8bf load_h8(const __bf16* p) {
    unsigned long long lo = __hip_atomic_load((unsigned long long*)p,     __ATOMIC_RELAXED, __HIP_MEMORY_SCOPE_AGENT);
    unsigned long long hi = __hip_atomic_load((unsigned long long*)p + 1, __ATOMIC_RELAXED, __HIP_MEMORY_SCOPE_AGENT);
    union { unsigned long long q[2]; v8bf v; } u;
    u.q[0] = lo; u.q[1] = hi;
    return u.v;
}

static __device__ __forceinline__ unsigned short bf16_bits(float f) {
    __bf16 b = (__bf16)f;
    return __builtin_bit_cast(unsigned short, b);
}

// ---- in-band generation-parity validation ----
// |h| <= 0.99609375 (clamped) => bit14 of every valid bf16 h is 0. Producer ORs
// bit14 = gen parity into each 16-bit half. Consumer: accept fragment iff every
// half has bit14 == expected parity, then clear bit14 (restores exact bits).
// Stale data (previous generation / init pattern) has wrong parity -> retry.
static __device__ __forceinline__ unsigned frag_chk_clr(v8bf* f, unsigned pm) {
    union { v8bf v; unsigned u[4]; } a; a.v = *f;
    unsigned bad = ((a.u[0] ^ pm) | (a.u[1] ^ pm) | (a.u[2] ^ pm) | (a.u[3] ^ pm)) & 0x40004000u;
    a.u[0] &= 0xBFFFBFFFu; a.u[1] &= 0xBFFFBFFFu;
    a.u[2] &= 0xBFFFBFFFu; a.u[3] &= 0xBFFFBFFFu;
    *f = a.v;
    return bad;
}

// Load 16 fragments, validate parity, clear tag bits; retry until all 64 lanes ok.
// Uses q/aoff from enclosing scope.
#define LOAD_VALIDATE16(dst_, base_, pm_)                                      \
    {                                                                          \
        const __bf16* _b  = (base_);                                           \
        const unsigned _pm = (pm_);                                            \
        while (true) {                                                         \
            _Pragma("unroll")                                                  \
            for (int c = 0; c < 16; ++c)                                       \
                dst_[c] = load_h8(_b + (4 * c + q) * 512 + aoff);              \
            __builtin_amdgcn_sched_barrier(0);                                 \
            unsigned _bad = 0u;                                                \
            _Pragma("unroll")                                                  \
            for (int c = 0; c < 16; ++c) _bad |= frag_chk_clr(&dst_[c], _pm);  \
            if (__all(_bad == 0u)) break;                                      \
        }                                                                      \
    }

// Combined 32-fragment variant (L2: h1[s] and h2[s-1] batches overlap in flight).
#define LOAD_VALIDATE32(d0_, b0_, pm0_, d1_, b1_, pm1_)                        \
    {                                                                          \
        const __bf16* _b0 = (b0_);                                             \
        const __bf16* _b1 = (b1_);                                             \
        const unsigned _p0 = (pm0_), _p1 = (pm1_);                             \
        while (true) {                                                         \
            _Pragma("unroll")                                                  \
            for (int c = 0; c < 16; ++c)                                       \
                d0_[c] = load_h8(_b0 + (4 * c + q) * 512 + aoff);              \
            _Pragma("unroll")                                                  \
            for (int c = 0; c < 16; ++c)                                       \
                d1_[c] = load_h8(_b1 + (4 * c + q) * 512 + aoff);              \
            __builtin_amdgcn_sched_barrier(0);                                 \
            unsigned _bad = 0u;                                                \
            _Pragma("unroll")                                                  \
            for (int c = 0; c < 16; ++c) _bad |= frag_chk_clr(&d0_[c], _p0);   \
            _Pragma("unroll")                                                  \
            for (int c = 0; c < 16; ++c) _bad |= frag_chk_clr(&d1_[c], _p1);   \
            if (__all(_bad == 0u)) break;                                      \
        }                                                                      \
    }

// ---------------- phase A: weight convert to fragment-linear bf16 ----------------
__global__ void wconv_kernel(const float* __restrict__ Wf, const float* __restrict__ Uf,
                             const float* __restrict__ Wb, const float* __restrict__ Ub,
                             char* __restrict__ dst, int NC, int KX)
{
    int id = blockIdx.x * 256 + threadIdx.x;
    int j    = id & 7;
    int lane = (id >> 3) & 63;
    int t    = (id >> 9) & 1;
    int rest = id >> 10;            // (dir*64+slice)*NC + c
    int c    = rest % NC;
    int ds   = rest / NC;
    int slice = ds & 63;
    int dirr  = ds >> 6;
    int coll = t * 16 + (lane & 15);
    int k    = c * 32 + (lane >> 4) * 8 + j;
    int gate = coll >> 3, jjj = coll & 7;
    int zcol = gate * 512 + slice * 8 + jjj;
    const float* W = dirr ? Wb : Wf;
    const float* U = dirr ? Ub : Uf;
    float v = (k < KX) ? W[(size_t)k * NG + zcol] : U[(size_t)(k - KX) * NG + zcol];
    ((__bf16*)dst)[id] = (__bf16)v;
}

// ---------------- phase A: embedding gather into fragment-linear X + ring/tag init ----------------
// X element (t, b=m, e) stored at byte: t*32768 + ((e>>3)*64 + m)*16 + (e&7)*2
__global__ void gather_x_kernel(const int* __restrict__ tokens, const float* __restrict__ emb,
                                char* __restrict__ ws)
{
    size_t id = (size_t)blockIdx.x * 256 + threadIdx.x;
    int j  = (int)(id & 7);
    int m  = (int)((id >> 3) & 63);
    int kb = (int)((id >> 9) & 31);
    int t  = (int)(id >> 14);
    int tok = tokens[m * TSEQ + t];
    float v = emb[(size_t)tok * NE + kb * 8 + j];
    ((__bf16*)(ws + OFF_X))[(size_t)t * 16384 + (kb * 64 + m) * 8 + j] = (__bf16)v;
    // ring init: bit14=1 pattern never validates for generation-0 (parity 0)
    if (id < 262144) ((unsigned*)(ws + OFF_H1))[id] = 0x40004000u;   // H1+H2, both dirs (1MB)
    if (id < 16384)  ((int*)(ws + OFF_CNT))[id] = 0;                 // all tag replicas
}

// ---------------- phase B: persistent pipelined recurrence ----------------
// Byte-identical to the proven R0 structure (ring depth 4, slot stride 32768 bf16,
// x16-replicated tags) EXCEPT publication is drain-free: producers store h with
// bit14 = generation parity (in-band tag) and publish the hint tags WITHOUT the
// s_waitcnt vmcnt(0) store-ack drain. Consumers spin on hints, then value-validate
// the loaded fragments (parity check) and retry in the rare data-lags-hint case.
template<int LAYER>
__device__ void run_layer(char* __restrict__ ws, const char* __restrict__ smem,
                          int dir, int slice, int tid,
                          const float* __restrict__ bb)
{
    const int lane = tid & 63;
    const int wv   = tid >> 6;
    const int colc = lane & 15;
    const int q    = lane >> 4;
    const int m0   = wv * 16;
    const int jj   = colc & 7;
    const int hcol = slice * 8 + jj;

    __bf16* h1ring = (__bf16*)(ws + OFF_H1 + (size_t)dir * (4 * 65536));
    __bf16* h2ring = (__bf16*)(ws + OFF_H2 + (size_t)dir * (4 * 65536));
    const char* Xfrag = ws + OFF_X;
    __bf16* hfin = (__bf16*)(ws + OFF_HF) + (size_t)dir * (NB * NH);

    // tags: T[(dir*2+layer)*4096 + rep*256 + wv*64 + slice]
    int* T = (int*)(ws + OFF_CNT);
    const int rep = ((slice << 2) | wv) & 15;
    int* p1   = T + (dir * 2 + 0) * 4096 + rep * 256 + wv * 64 + lane;   // poll L1 producers
    int* p2   = T + (dir * 2 + 1) * 4096 + rep * 256 + wv * 64 + lane;   // poll L2 producers
    int* ownb = T + (dir * 2 + LAYER) * 4096;                             // publish base

    const float bi  = bb[hcol];
    const float bf_ = bb[512 + hcol];
    const float bg  = bb[1024 + hcol];
    const float bo  = bb[1536 + hcol];

    float cst[4] = {0.f, 0.f, 0.f, 0.f};

    // h-fragment element offset for consumer loads (in __bf16 units)
    const int aoff = (m0 + colc) * 8;

    #pragma unroll 1
    for (int s = 0; s < TSEQ; ++s) {
        v4f acc0a = {0,0,0,0}, acc1a = {0,0,0,0};
        v4f acc0b = {0,0,0,0}, acc1b = {0,0,0,0};

        // parity masks: slot = x & 3, generation parity = (x >> 2) & 1
        const unsigned pmW  = ((s >> 2) & 1)       ? 0x40004000u : 0u;   // write step s
        const unsigned pmRp = (((s - 1) >> 2) & 1) ? 0x40004000u : 0u;   // read step s-1

        // ---- L1: x-part (no step dependency) computed BEFORE the poll ----
        if (LAYER == 0) {
            const int xs = dir ? (TSEQ - 1 - s) : s;
            const char* xb = Xfrag + (size_t)xs * 32768;
            #pragma unroll
            for (int c = 0; c < 8; ++c) {
                v8bf a  = *(const v8bf*)(xb + (((4 * c + q) * 64 + m0 + colc) * 16));
                v8bf w0 = *(const v8bf*)(smem + (c * 2 + 0) * 1024 + lane * 16);
                v8bf w1 = *(const v8bf*)(smem + (c * 2 + 1) * 1024 + lane * 16);
                if (c & 1) { acc0b = MFMA16(a, w0, acc0b); acc1b = MFMA16(a, w1, acc1b); }
                else       { acc0a = MFMA16(a, w0, acc0a); acc1a = MFMA16(a, w1, acc1a); }
            }
        }

        // ---- lane-parallel poll on replicated per-wave tags ----
        // L1 step s: p1 >= s (h1[s-1] issued), p2 >= s-3 (ring guard)
        // L2 step s: p1 >= s+1 (h1[s] issued), p2 >= s (h2[s-1] issued)
        {
            const int t1 = LAYER ? s + 1 : s;
            const int t2 = LAYER ? s : s - 3;
            if (t1 > 0) {
                while (true) {
                    int v1 = __hip_atomic_load(p1, __ATOMIC_RELAXED, __HIP_MEMORY_SCOPE_AGENT);
                    bool ok = (v1 >= t1);
                    if (t2 > 0) {
                        int v2 = __hip_atomic_load(p2, __ATOMIC_RELAXED, __HIP_MEMORY_SCOPE_AGENT);
                        ok = ok && (v2 >= t2);
                    }
                    if (__all(ok)) break;
                }
            }
        }

        // ---- h-dependent MFMA work (validated coherent loads, LDS weights) ----
        if (LAYER == 0) {
            if (s > 0) {
                v8bf ah[16];
                LOAD_VALIDATE16(ah, h1ring + (size_t)((s - 1) & 3) * 32768, pmRp);
                #pragma unroll
                for (int c = 0; c < 16; ++c) {
                    v8bf w0 = *(const v8bf*)(smem + ((8 + c) * 2 + 0) * 1024 + lane * 16);
                    v8bf w1 = *(const v8bf*)(smem + ((8 + c) * 2 + 1) * 1024 + lane * 16);
                    if (c & 1) { acc0b = MFMA16(ah[c], w0, acc0b); acc1b = MFMA16(ah[c], w1, acc1b); }
                    else       { acc0a = MFMA16(ah[c], w0, acc0a); acc1a = MFMA16(ah[c], w1, acc1a); }
                }
            }
        } else {
            const unsigned pmRc = pmW;   // read h1[s]: same slot/parity as step s
            v8bf a0[16], a1[16];
            if (s > 0) {
                LOAD_VALIDATE32(a0, h1ring + (size_t)(s & 3) * 32768, pmRc,
                                a1, h2ring + (size_t)((s - 1) & 3) * 32768, pmRp);
            } else {
                LOAD_VALIDATE16(a0, h1ring + (size_t)(s & 3) * 32768, pmRc);
            }
            #pragma unroll
            for (int c = 0; c < 16; ++c) {
                v8bf w0 = *(const v8bf*)(smem + (c * 2 + 0) * 1024 + lane * 16);
                v8bf w1 = *(const v8bf*)(smem + (c * 2 + 1) * 1024 + lane * 16);
                if (c & 1) { acc0b = MFMA16(a0[c], w0, acc0b); acc1b = MFMA16(a0[c], w1, acc1b); }
                else       { acc0a = MFMA16(a0[c], w0, acc0a); acc1a = MFMA16(a0[c], w1, acc1a); }
            }
            if (s > 0) {
                #pragma unroll
                for (int c = 0; c < 16; ++c) {
                    v8bf w0 = *(const v8bf*)(smem + ((16 + c) * 2 + 0) * 1024 + lane * 16);
                    v8bf w1 = *(const v8bf*)(smem + ((16 + c) * 2 + 1) * 1024 + lane * 16);
                    if (c & 1) { acc0b = MFMA16(a1[c], w0, acc0b); acc1b = MFMA16(a1[c], w1, acc1b); }
                    else       { acc0a = MFMA16(a1[c], w0, acc0a); acc1a = MFMA16(a1[c], w1, acc1a); }
                }
            }
        }

        v4f z0 = acc0a + acc0b;   // gates i (cols 0-7) / f (cols 8-15)
        v4f z1 = acc1a + acc1b;   // gates g / o

        // ---- gate nonlinearity; lanes col and col^8 exchange ----
        float hv[4];
        #pragma unroll
        for (int r = 0; r < 4; ++r) {
            float p0 = __shfl_xor(z0[r], 8, 64);
            float p1v = __shfl_xor(z1[r], 8, 64);
            float zi, zf, zg, zo;
            if (colc < 8) { zi = z0[r]; zf = p0;    zg = z1[r]; zo = p1v;   }
            else          { zi = p0;    zf = z0[r]; zg = p1v;   zo = z1[r]; }
            zi += bi; zf += bf_; zg += bg; zo += bo;
            float gi = 1.f / (1.f + __expf(-zi));
            float gf = 1.f / (1.f + __expf(-zf));
            float gg = 1.f - 2.f / (1.f + __expf(2.f * zg));   // tanh
            float go = 1.f / (1.f + __expf(-zo));
            float cn = gf * cst[r] + gi * gg;
            cst[r] = cn;
            float th = 1.f - 2.f / (1.f + __expf(2.f * cn));   // tanh
            // clamp to largest bf16 < 1.0 so bit14 stays 0 (in-band tag invariant);
            // only acts when |h| >= 0.998 (~12 sigma here), error <= 0.004 if ever hit
            hv[r] = fminf(fmaxf(go * th, -0.99609375f), 0.99609375f);
        }

        // ---- drain-free publication: h store with bit14 = gen parity, then hints ----
        __bf16* hd = (LAYER ? h2ring : h1ring) + (size_t)(s & 3) * 32768;
        #pragma unroll
        for (int r = 0; r < 4; ++r) {
            float pv = __shfl_xor(hv[r], 1, 64);
            int m = m0 + q * 4 + r;
            if (((colc & 1) == 0) && (colc < 8)) {
                unsigned val = ((unsigned)bf16_bits(hv[r]) | ((unsigned)bf16_bits(pv) << 16)) | pmW;
                __hip_atomic_store((unsigned*)(hd + (slice * 64 + m) * 8 + colc), val,
                                   __ATOMIC_RELAXED, __HIP_MEMORY_SCOPE_AGENT);
            }
            if (LAYER == 1 && s == TSEQ - 1 && colc < 8)
                hfin[(size_t)m * NH + hcol] = (__bf16)hv[r];   // kernel boundary publishes
        }

        // hints AFTER data in program order (no waitcnt — consumers validate)
        __builtin_amdgcn_sched_barrier(0);
        if (lane < 16)
            __hip_atomic_store(ownb + lane * 256 + wv * 64 + slice, s + 1,
                               __ATOMIC_RELAXED, __HIP_MEMORY_SCOPE_AGENT);
    }
}

__global__ __launch_bounds__(256, 1) void lstm_persist(
    char* __restrict__ ws,
    const float* __restrict__ b1f, const float* __restrict__ b2f,
    const float* __restrict__ b1b, const float* __restrict__ b2b)
{
    const int tid   = threadIdx.x;
    const int bid   = blockIdx.x;       // 256 wgs
    const int dir   = bid >> 7;
    const int layer = (bid >> 6) & 1;
    const int slice = bid & 63;

    const int NC = layer ? 32 : 24;
    const int wbytes = NC * 2048;       // 48KB (L1) / 64KB (L2)

    __shared__ char smem[65536];
    {
        const char* wsrc = ws + (layer ? OFF_W2 : OFF_W1)
                         + (size_t)(dir * 64 + slice) * (size_t)wbytes;
        for (int i = tid * 16; i < wbytes; i += 256 * 16)
            *(uint4*)(smem + i) = *(const uint4*)(wsrc + i);
    }
    __syncthreads();   // staging is cooperative; only barrier in the kernel

    const float* bb = layer ? (dir ? b2b : b2f) : (dir ? b1b : b1f);
    if (layer == 0) run_layer<0>(ws, smem, dir, slice, tid, bb);
    else            run_layer<1>(ws, smem, dir, slice, tid, bb);
}

// ---------------- phase C: dense head [64,1024]@[1024,5]+bd ----------------
__global__ void head_kernel(const char* __restrict__ ws, const float* __restrict__ Wd,
                            const float* __restrict__ bd, float* __restrict__ out)
{
    int b = blockIdx.x;
    int lane = threadIdx.x;   // 64
    const __bf16* hfF = (const __bf16*)(ws + OFF_HF) + (size_t)b * NH;
    const __bf16* hfB = (const __bf16*)(ws + OFF_HF) + (size_t)(NB * NH) + (size_t)b * NH;
    #pragma unroll
    for (int o = 0; o < 5; ++o) {
        float sum = 0.f;
        for (int k = lane; k < 2 * NH; k += 64) {
            float fv = (k < NH) ? (float)hfF[k] : (float)hfB[k - NH];
            sum += fv * Wd[(size_t)k * 5 + o];
        }
        #pragma unroll
        for (int off = 32; off > 0; off >>= 1) sum += __shfl_down(sum, off, 64);
        if (lane == 0) out[b * 5 + o] = sum + bd[o];
    }
}

// ---------------- launch ----------------
extern "C" void kernel_launch(void* const* d_in, const int* in_sizes, int n_in,
                              void* d_out, int out_size, void* d_ws, size_t ws_size,
                              hipStream_t stream)
{
    const int*   tokens = (const int*)  d_in[0];
    const float* emb    = (const float*)d_in[1];
    const float* W1f    = (const float*)d_in[2];
    const float* U1f    = (const float*)d_in[3];
    const float* b1f    = (const float*)d_in[4];
    const float* W2f    = (const float*)d_in[5];
    const float* U2f    = (const float*)d_in[6];
    const float* b2f    = (const float*)d_in[7];
    const float* W1b    = (const float*)d_in[8];
    const float* U1b    = (const float*)d_in[9];
    const float* b1b    = (const float*)d_in[10];
    const float* W2b    = (const float*)d_in[11];
    const float* U2b    = (const float*)d_in[12];
    const float* b2b    = (const float*)d_in[13];
    const float* Wd     = (const float*)d_in[14];
    const float* bd     = (const float*)d_in[15];
    char* ws = (char*)d_ws;

    wconv_kernel<<<12288, 256, 0, stream>>>(W1f, U1f, W1b, U1b, ws + OFF_W1, 24, 256);
    wconv_kernel<<<16384, 256, 0, stream>>>(W2f, U2f, W2b, U2b, ws + OFF_W2, 32, 512);
    gather_x_kernel<<<32768, 256, 0, stream>>>(tokens, emb, ws);
    lstm_persist<<<256, 256, 0, stream>>>(ws, b1f, b2f, b1b, b2b);
    head_kernel<<<NB, 64, 0, stream>>>(ws, Wd, bd, (float*)d_out);
}